// Round 1
// baseline (398.044 us; speedup 1.0000x reference)
//
#include <hip/hip_runtime.h>
#include <stdint.h>

#define B_ 4
#define C_ 256
#define H_ 64
#define W_ 64
#define O_ 256
#define K_ 2304    // C_*9, tap-major: kk = k*256 + c
#define HW 4096
#define NPIX 16384

typedef unsigned short u16;
typedef __attribute__((ext_vector_type(8))) short bf16x8;
typedef __attribute__((ext_vector_type(4))) float f32x4;

__device__ __forceinline__ u16 f2bf(float f) {
    union { float f; uint32_t u; } v; v.f = f;
    uint32_t u = v.u;
    return (u16)((u + 0x7FFFu + ((u >> 16) & 1u)) >> 16);
}

// ---------------- Kernel 1: scale + mask conv3x3 ----------------
// grid (B*H) blocks, 512 threads: lane (tid&63) = w pixel, wave (tid>>6) = channel group of 32.
__global__ __launch_bounds__(512) void k_scale_mask(
    const float* __restrict__ x, const float* __restrict__ w_scale,
    const float* __restrict__ b_scale, const float* __restrict__ w_mask,
    const float* __restrict__ b_mask, float* __restrict__ scale_o,
    float* __restrict__ mask_o)
{
    int bh = blockIdx.x;           // 0..255
    int b = bh >> 6, h = bh & 63;
    int tid = threadIdx.x;
    int w = tid & 63;
    int wv = tid >> 6;             // 0..7

    float acc[10];
#pragma unroll
    for (int o = 0; o < 10; ++o) acc[o] = 0.f;

    const float* xb = x + (size_t)b * (C_ * HW);
    for (int cc = 0; cc < 32; ++cc) {
        int c = wv * 32 + cc;
        const float* xp = xb + c * HW;
        float xv[9];
#pragma unroll
        for (int dy = -1; dy <= 1; ++dy) {
            int hh = h + dy;
            bool hv = (hh >= 0) && (hh < 64);
#pragma unroll
            for (int dx = -1; dx <= 1; ++dx) {
                int ww = w + dx;
                bool vld = hv && (ww >= 0) && (ww < 64);
                xv[(dy + 1) * 3 + (dx + 1)] = vld ? xp[hh * 64 + ww] : 0.f;
            }
        }
        const float* wsc = w_scale + c * 9;
#pragma unroll
        for (int k = 0; k < 9; ++k) acc[0] = fmaf(xv[k], wsc[k], acc[0]);
#pragma unroll
        for (int j = 0; j < 9; ++j) {
            const float* wm = w_mask + ((size_t)(j * C_ + c)) * 9;
#pragma unroll
            for (int k = 0; k < 9; ++k) acc[1 + j] = fmaf(xv[k], wm[k], acc[1 + j]);
        }
    }

    __shared__ float red[10 * 8 * 64];
#pragma unroll
    for (int o = 0; o < 10; ++o) red[(o * 8 + wv) * 64 + w] = acc[o];
    __syncthreads();
    if (tid < 64) {
#pragma unroll
        for (int o = 0; o < 10; ++o) {
            float t = 0.f;
#pragma unroll
            for (int g = 0; g < 8; ++g) t += red[(o * 8 + g) * 64 + tid];
            if (o == 0) {
                float s = t + b_scale[0];
                scale_o[bh * 64 + tid] = s > 0.f ? s : 0.f;   // relu * BASE_DILATION(1.0)
            } else {
                float m = t + b_mask[o - 1];
                mask_o[(b * 9 + (o - 1)) * HW + (bh & 63) * 64 + tid] =
                    1.f / (1.f + expf(-m));
            }
        }
    }
}

// ---------------- Kernel 2: pack weight fp32 -> bf16, tap-major K ----------------
// grid (9, 256): bx = k, by = o; tid = c.  wbf[o][k*256+c] = weight[o][c][k]
__global__ __launch_bounds__(256) void k_pack_w(const float* __restrict__ wgt,
                                                u16* __restrict__ wbf)
{
    int k = blockIdx.x, o = blockIdx.y, c = threadIdx.x;
    wbf[(size_t)o * K_ + k * 256 + c] = f2bf(wgt[(size_t)o * K_ + c * 9 + k]);
}

// ---------------- Kernel 3: build val[N][K] bf16 (pixel-major) ----------------
// grid (3, B*H): bx = tap-group (3 taps), by = bh. 256 threads: lane = w, wave = 64-ch group.
__global__ __launch_bounds__(256) void k_val(
    const float* __restrict__ x, const float* __restrict__ scale_i,
    const float* __restrict__ mask_i, u16* __restrict__ val)
{
    int bh = blockIdx.y;
    int b = bh >> 6, h = bh & 63;
    int sub = blockIdx.x;          // dy = sub-1
    int tid = threadIdx.x;
    int w = tid & 63;
    int wv = tid >> 6;             // 0..3 -> channels [wv*64, wv*64+64)
    int p = bh * 64 + w;

    float s = scale_i[p];
    float d = 1.f + s;
    const float* xb = x + (size_t)b * (C_ * HW);
    u16* vrow = val + (size_t)p * K_;

    float dyf = (float)(sub - 1);
    float ysf = (float)(h - 1) + dyf * d;

#pragma unroll
    for (int kt = 0; kt < 3; ++kt) {
        int k = sub * 3 + kt;
        float dxf = (float)(kt - 1);
        float xsf = (float)(w - 1) + dxf * d;

        float y0f = floorf(ysf), x0f = floorf(xsf);
        float wy = ysf - y0f, wx = xsf - x0f;
        int y0 = (int)y0f, x0 = (int)x0f;
        int y1 = y0 + 1, x1 = x0 + 1;
        float vy0 = (y0 >= 0 && y0 < 64) ? 1.f : 0.f;
        float vy1 = (y1 >= 0 && y1 < 64) ? 1.f : 0.f;
        float vx0 = (x0 >= 0 && x0 < 64) ? 1.f : 0.f;
        float vx1 = (x1 >= 0 && x1 < 64) ? 1.f : 0.f;

        float m = mask_i[(b * 9 + k) * HW + h * 64 + w];
        float w00 = (1.f - wy) * (1.f - wx) * m * vy0 * vx0;
        float w01 = (1.f - wy) * wx * m * vy0 * vx1;
        float w10 = wy * (1.f - wx) * m * vy1 * vx0;
        float w11 = wy * wx * m * vy1 * vx1;

        int cy0 = min(max(y0, 0), 63), cy1 = min(max(y1, 0), 63);
        int cx0 = min(max(x0, 0), 63), cx1 = min(max(x1, 0), 63);
        int i00 = cy0 * 64 + cx0, i01 = cy0 * 64 + cx1;
        int i10 = cy1 * 64 + cx0, i11 = cy1 * 64 + cx1;

        u16* vout = vrow + k * 256 + wv * 64;
        for (int c8 = 0; c8 < 8; ++c8) {
            union { u16 u[8]; uint4 v; } pk;
#pragma unroll
            for (int cc = 0; cc < 8; ++cc) {
                int c = wv * 64 + c8 * 8 + cc;
                const float* xp = xb + c * HW;
                float vf = w00 * xp[i00] + w01 * xp[i01] + w10 * xp[i10] + w11 * xp[i11];
                pk.u[cc] = f2bf(vf);
            }
            *(uint4*)(vout + c8 * 8) = pk.v;
        }
    }
}

// ---------------- Kernel 4: bf16 MFMA GEMM ----------------
// C[o][p] = sum_k Wbf[o][k] * Val[p][k]  (both row-major over K -> B^T GEMM)
// BM=BN=128, BK=32, 4 waves (2x2), each wave 64x64 via 4x4 fragments of 16x16x32.
__global__ __launch_bounds__(256) void k_gemm(
    const u16* __restrict__ wbf, const u16* __restrict__ val,
    const float* __restrict__ bias, float* __restrict__ out)
{
    __shared__ u16 As[128 * 40];
    __shared__ u16 Bs[128 * 40];
    int tid = threadIdx.x;
    int lane = tid & 63;
    int wv = tid >> 6;
    int wm = wv >> 1, wn = wv & 1;
    int n0 = blockIdx.x * 128;
    int m0 = blockIdx.y * 128;
    int l15 = lane & 15, l4 = lane >> 4;

    f32x4 acc[4][4];
#pragma unroll
    for (int i = 0; i < 4; ++i)
#pragma unroll
        for (int j = 0; j < 4; ++j) acc[i][j] = (f32x4){0.f, 0.f, 0.f, 0.f};

    int r0 = tid >> 2, q0 = tid & 3;
    int r1 = (tid + 256) >> 2;   // q1 == q0

    for (int k0 = 0; k0 < K_; k0 += 32) {
        uint4 a0 = *(const uint4*)(wbf + (size_t)(m0 + r0) * K_ + k0 + q0 * 8);
        uint4 a1 = *(const uint4*)(wbf + (size_t)(m0 + r1) * K_ + k0 + q0 * 8);
        uint4 b0 = *(const uint4*)(val + (size_t)(n0 + r0) * K_ + k0 + q0 * 8);
        uint4 b1 = *(const uint4*)(val + (size_t)(n0 + r1) * K_ + k0 + q0 * 8);
        __syncthreads();           // protect previous iteration's LDS reads
        *(uint4*)(As + r0 * 40 + q0 * 8) = a0;
        *(uint4*)(As + r1 * 40 + q0 * 8) = a1;
        *(uint4*)(Bs + r0 * 40 + q0 * 8) = b0;
        *(uint4*)(Bs + r1 * 40 + q0 * 8) = b1;
        __syncthreads();

        bf16x8 af[4], bg[4];
#pragma unroll
        for (int i = 0; i < 4; ++i)
            af[i] = *(const bf16x8*)(As + (wm * 64 + i * 16 + l15) * 40 + l4 * 8);
#pragma unroll
        for (int j = 0; j < 4; ++j)
            bg[j] = *(const bf16x8*)(Bs + (wn * 64 + j * 16 + l15) * 40 + l4 * 8);
#pragma unroll
        for (int i = 0; i < 4; ++i)
#pragma unroll
            for (int j = 0; j < 4; ++j)
                acc[i][j] = __builtin_amdgcn_mfma_f32_16x16x32_bf16(af[i], bg[j], acc[i][j], 0, 0, 0);
    }

    int bidx = n0 >> 12;           // batch index (128 | 4096)
    int hwbase = n0 & 4095;
#pragma unroll
    for (int i = 0; i < 4; ++i)
#pragma unroll
        for (int j = 0; j < 4; ++j)
#pragma unroll
            for (int t = 0; t < 4; ++t) {
                int row = wm * 64 + i * 16 + l4 * 4 + t;
                int col = wn * 64 + j * 16 + l15;
                int o = m0 + row;
                out[((size_t)(bidx * O_ + o)) * HW + hwbase + col] = acc[i][j][t] + bias[o];
            }
}

extern "C" void kernel_launch(void* const* d_in, const int* in_sizes, int n_in,
                              void* d_out, int out_size, void* d_ws, size_t ws_size,
                              hipStream_t stream) {
    const float* x       = (const float*)d_in[0];
    const float* weight  = (const float*)d_in[1];
    const float* bias    = (const float*)d_in[2];
    const float* w_scale = (const float*)d_in[3];
    const float* b_scale = (const float*)d_in[4];
    const float* w_mask  = (const float*)d_in[5];
    const float* b_mask  = (const float*)d_in[6];
    float* out = (float*)d_out;

    char* ws = (char*)d_ws;
    float* scale_ws = (float*)ws;                              // 16384 f32  = 64 KB
    float* mask_ws  = (float*)(ws + 65536);                    // 147456 f32 = 576 KB
    u16*   wbf      = (u16*)(ws + 65536 + 589824);             // 589824 bf16
    u16*   val      = (u16*)(ws + 65536 + 589824 + 1179648);   // 16384*2304 bf16 = 75.5 MB

    k_scale_mask<<<dim3(B_ * H_), 512, 0, stream>>>(x, w_scale, b_scale, w_mask, b_mask,
                                                    scale_ws, mask_ws);
    k_pack_w<<<dim3(9, O_), 256, 0, stream>>>(weight, wbf);
    k_val<<<dim3(3, B_ * H_), 256, 0, stream>>>(x, scale_ws, mask_ws, val);
    k_gemm<<<dim3(NPIX / 128, O_ / 128), 256, 0, stream>>>(wbf, val, bias, out);
}

// Round 2
// 217.793 us; speedup vs baseline: 1.8276x; 1.8276x over previous
//
#include <hip/hip_runtime.h>
#include <stdint.h>

#define B_ 4
#define C_ 256
#define H_ 64
#define W_ 64
#define O_ 256
#define K_ 2304    // C_*9, tap-major: kk = k*256 + c
#define HW 4096
#define NPIX 16384

typedef unsigned short u16;
typedef __attribute__((ext_vector_type(8))) short bf16x8;
typedef __attribute__((ext_vector_type(4))) float f32x4;

__device__ __forceinline__ u16 f2bf(float f) {
    union { float f; uint32_t u; } v; v.f = f;
    uint32_t u = v.u;
    return (u16)((u + 0x7FFFu + ((u >> 16) & 1u)) >> 16);
}

// ---------------- Kernel 1: scale + mask conv3x3 ----------------
__global__ __launch_bounds__(512) void k_scale_mask(
    const float* __restrict__ x, const float* __restrict__ w_scale,
    const float* __restrict__ b_scale, const float* __restrict__ w_mask,
    const float* __restrict__ b_mask, float* __restrict__ scale_o,
    float* __restrict__ mask_o)
{
    int bh = blockIdx.x;           // 0..255
    int b = bh >> 6, h = bh & 63;
    int tid = threadIdx.x;
    int w = tid & 63;
    int wv = tid >> 6;             // 0..7

    float acc[10];
#pragma unroll
    for (int o = 0; o < 10; ++o) acc[o] = 0.f;

    const float* xb = x + (size_t)b * (C_ * HW);
    for (int cc = 0; cc < 32; ++cc) {
        int c = wv * 32 + cc;
        const float* xp = xb + c * HW;
        float xv[9];
#pragma unroll
        for (int dy = -1; dy <= 1; ++dy) {
            int hh = h + dy;
            bool hv = (hh >= 0) && (hh < 64);
#pragma unroll
            for (int dx = -1; dx <= 1; ++dx) {
                int ww = w + dx;
                bool vld = hv && (ww >= 0) && (ww < 64);
                xv[(dy + 1) * 3 + (dx + 1)] = vld ? xp[hh * 64 + ww] : 0.f;
            }
        }
        const float* wsc = w_scale + c * 9;
#pragma unroll
        for (int k = 0; k < 9; ++k) acc[0] = fmaf(xv[k], wsc[k], acc[0]);
#pragma unroll
        for (int j = 0; j < 9; ++j) {
            const float* wm = w_mask + ((size_t)(j * C_ + c)) * 9;
#pragma unroll
            for (int k = 0; k < 9; ++k) acc[1 + j] = fmaf(xv[k], wm[k], acc[1 + j]);
        }
    }

    __shared__ float red[10 * 8 * 64];
#pragma unroll
    for (int o = 0; o < 10; ++o) red[(o * 8 + wv) * 64 + w] = acc[o];
    __syncthreads();
    if (tid < 64) {
#pragma unroll
        for (int o = 0; o < 10; ++o) {
            float t = 0.f;
#pragma unroll
            for (int g = 0; g < 8; ++g) t += red[(o * 8 + g) * 64 + tid];
            if (o == 0) {
                float s = t + b_scale[0];
                scale_o[bh * 64 + tid] = s > 0.f ? s : 0.f;
            } else {
                float m = t + b_mask[o - 1];
                mask_o[(b * 9 + (o - 1)) * HW + (bh & 63) * 64 + tid] =
                    1.f / (1.f + expf(-m));
            }
        }
    }
}

// ---------------- Kernel 2: pack weight fp32 -> bf16, tap-major K ----------------
__global__ __launch_bounds__(256) void k_pack_w(const float* __restrict__ wgt,
                                                u16* __restrict__ wbf)
{
    int k = blockIdx.x, o = blockIdx.y, c = threadIdx.x;
    wbf[(size_t)o * K_ + k * 256 + c] = f2bf(wgt[(size_t)o * K_ + c * 9 + k]);
}

// ---------------- Kernel 2b: transpose x NCHW -> NHWC (xT[b][hw][c]) ----------------
// grid (64, 4, 4): (hw-tile of 64, c-tile of 64, b). 256 threads.
__global__ __launch_bounds__(256) void k_transpose(const float* __restrict__ x,
                                                   float* __restrict__ xT)
{
    __shared__ float t[64][65];
    int tid = threadIdx.x;
    int hw0 = blockIdx.x * 64, c0 = blockIdx.y * 64, b = blockIdx.z;

    // load: lanes cover 4-contig hw, 16 c-rows per iter
    {
        int hw4 = (tid & 15) * 4;
        int cr = tid >> 4;                 // 0..15
        const float* xb = x + ((size_t)(b * 256 + c0)) * HW + hw0;
#pragma unroll
        for (int i = 0; i < 4; ++i) {
            int c = cr + i * 16;
            float4 v = *(const float4*)(xb + (size_t)c * HW + hw4);
            *(float4*)(&t[c][hw4]) = v;
        }
    }
    __syncthreads();
    // store: lanes cover 4-contig c, 16 hw-rows per iter
    {
        int c4 = (tid & 15) * 4;
        int hwr = tid >> 4;                // 0..15
        float* xo = xT + ((size_t)(b * HW + hw0)) * 256 + c0;
#pragma unroll
        for (int i = 0; i < 4; ++i) {
            int hwl = hwr + i * 16;
            float4 o;
            o.x = t[c4 + 0][hwl];
            o.y = t[c4 + 1][hwl];
            o.z = t[c4 + 2][hwl];
            o.w = t[c4 + 3][hwl];
            *(float4*)(xo + (size_t)hwl * 256 + c4) = o;
        }
    }
}

// ---------------- Kernel 3: build val[N][K] bf16 from NHWC x ----------------
// wave per pixel, lane per channel-quad; loop 9 taps. grid NPIX/4 blocks of 256.
__global__ __launch_bounds__(256) void k_val2(
    const float* __restrict__ xT, const float* __restrict__ scale_i,
    const float* __restrict__ mask_i, u16* __restrict__ val)
{
    int wv = threadIdx.x >> 6, lane = threadIdx.x & 63;
    int p = blockIdx.x * 4 + wv;
    int b = p >> 12, hw = p & 4095;
    int h = hw >> 6, w = hw & 63;
    float d = 1.f + scale_i[p];
    const float* xb = xT + ((size_t)(b << 12)) * 256;
    u16* vout = val + (size_t)p * K_;
    int c0 = lane * 4;

#pragma unroll 3
    for (int k = 0; k < 9; ++k) {
        int dy = k / 3 - 1, dx = k % 3 - 1;
        float ysf = (float)(h - 1) + (float)dy * d;
        float xsf = (float)(w - 1) + (float)dx * d;
        float y0f = floorf(ysf), x0f = floorf(xsf);
        float wy = ysf - y0f, wx = xsf - x0f;
        int y0 = (int)y0f, x0 = (int)x0f;
        int y1 = y0 + 1, x1 = x0 + 1;
        float vy0 = (y0 >= 0 && y0 < 64) ? 1.f : 0.f;
        float vy1 = (y1 >= 0 && y1 < 64) ? 1.f : 0.f;
        float vx0 = (x0 >= 0 && x0 < 64) ? 1.f : 0.f;
        float vx1 = (x1 >= 0 && x1 < 64) ? 1.f : 0.f;

        float m = mask_i[(b * 9 + k) * HW + hw];
        float w00 = (1.f - wy) * (1.f - wx) * m * vy0 * vx0;
        float w01 = (1.f - wy) * wx * m * vy0 * vx1;
        float w10 = wy * (1.f - wx) * m * vy1 * vx0;
        float w11 = wy * wx * m * vy1 * vx1;

        int cy0 = min(max(y0, 0), 63), cy1 = min(max(y1, 0), 63);
        int cx0 = min(max(x0, 0), 63), cx1 = min(max(x1, 0), 63);

        const float* p00 = xb + (size_t)(cy0 * 64 + cx0) * 256 + c0;
        const float* p01 = xb + (size_t)(cy0 * 64 + cx1) * 256 + c0;
        const float* p10 = xb + (size_t)(cy1 * 64 + cx0) * 256 + c0;
        const float* p11 = xb + (size_t)(cy1 * 64 + cx1) * 256 + c0;
        float4 v00 = *(const float4*)p00;
        float4 v01 = *(const float4*)p01;
        float4 v10 = *(const float4*)p10;
        float4 v11 = *(const float4*)p11;

        float rx = fmaf(w00, v00.x, fmaf(w01, v01.x, fmaf(w10, v10.x, w11 * v11.x)));
        float ry = fmaf(w00, v00.y, fmaf(w01, v01.y, fmaf(w10, v10.y, w11 * v11.y)));
        float rz = fmaf(w00, v00.z, fmaf(w01, v01.z, fmaf(w10, v10.z, w11 * v11.z)));
        float rw = fmaf(w00, v00.w, fmaf(w01, v01.w, fmaf(w10, v10.w, w11 * v11.w)));

        ushort4 pk;
        pk.x = f2bf(rx); pk.y = f2bf(ry); pk.z = f2bf(rz); pk.w = f2bf(rw);
        *(ushort4*)(vout + k * 256 + c0) = pk;
    }
}

// ---------------- Kernel 4: bf16 MFMA GEMM ----------------
__global__ __launch_bounds__(256) void k_gemm(
    const u16* __restrict__ wbf, const u16* __restrict__ val,
    const float* __restrict__ bias, float* __restrict__ out)
{
    __shared__ u16 As[128 * 40];
    __shared__ u16 Bs[128 * 40];
    int tid = threadIdx.x;
    int lane = tid & 63;
    int wv = tid >> 6;
    int wm = wv >> 1, wn = wv & 1;
    int n0 = blockIdx.x * 128;
    int m0 = blockIdx.y * 128;
    int l15 = lane & 15, l4 = lane >> 4;

    f32x4 acc[4][4];
#pragma unroll
    for (int i = 0; i < 4; ++i)
#pragma unroll
        for (int j = 0; j < 4; ++j) acc[i][j] = (f32x4){0.f, 0.f, 0.f, 0.f};

    int r0 = tid >> 2, q0 = tid & 3;
    int r1 = (tid + 256) >> 2;

    for (int k0 = 0; k0 < K_; k0 += 32) {
        uint4 a0 = *(const uint4*)(wbf + (size_t)(m0 + r0) * K_ + k0 + q0 * 8);
        uint4 a1 = *(const uint4*)(wbf + (size_t)(m0 + r1) * K_ + k0 + q0 * 8);
        uint4 b0 = *(const uint4*)(val + (size_t)(n0 + r0) * K_ + k0 + q0 * 8);
        uint4 b1 = *(const uint4*)(val + (size_t)(n0 + r1) * K_ + k0 + q0 * 8);
        __syncthreads();
        *(uint4*)(As + r0 * 40 + q0 * 8) = a0;
        *(uint4*)(As + r1 * 40 + q0 * 8) = a1;
        *(uint4*)(Bs + r0 * 40 + q0 * 8) = b0;
        *(uint4*)(Bs + r1 * 40 + q0 * 8) = b1;
        __syncthreads();

        bf16x8 af[4], bg[4];
#pragma unroll
        for (int i = 0; i < 4; ++i)
            af[i] = *(const bf16x8*)(As + (wm * 64 + i * 16 + l15) * 40 + l4 * 8);
#pragma unroll
        for (int j = 0; j < 4; ++j)
            bg[j] = *(const bf16x8*)(Bs + (wn * 64 + j * 16 + l15) * 40 + l4 * 8);
#pragma unroll
        for (int i = 0; i < 4; ++i)
#pragma unroll
            for (int j = 0; j < 4; ++j)
                acc[i][j] = __builtin_amdgcn_mfma_f32_16x16x32_bf16(af[i], bg[j], acc[i][j], 0, 0, 0);
    }

    int bidx = n0 >> 12;
    int hwbase = n0 & 4095;
#pragma unroll
    for (int i = 0; i < 4; ++i)
#pragma unroll
        for (int j = 0; j < 4; ++j)
#pragma unroll
            for (int t = 0; t < 4; ++t) {
                int row = wm * 64 + i * 16 + l4 * 4 + t;
                int col = wn * 64 + j * 16 + l15;
                int o = m0 + row;
                out[((size_t)(bidx * O_ + o)) * HW + hwbase + col] = acc[i][j][t] + bias[o];
            }
}

extern "C" void kernel_launch(void* const* d_in, const int* in_sizes, int n_in,
                              void* d_out, int out_size, void* d_ws, size_t ws_size,
                              hipStream_t stream) {
    const float* x       = (const float*)d_in[0];
    const float* weight  = (const float*)d_in[1];
    const float* bias    = (const float*)d_in[2];
    const float* w_scale = (const float*)d_in[3];
    const float* b_scale = (const float*)d_in[4];
    const float* w_mask  = (const float*)d_in[5];
    const float* b_mask  = (const float*)d_in[6];
    float* out = (float*)d_out;

    char* ws = (char*)d_ws;
    float* scale_ws = (float*)ws;                                  // 64 KB
    float* mask_ws  = (float*)(ws + 65536);                        // 576 KB
    u16*   wbf      = (u16*)(ws + 65536 + 589824);                 // 1.125 MB
    u16*   val      = (u16*)(ws + 65536 + 589824 + 1179648);       // 75.5 MB
    float* xT       = (float*)(ws + 65536 + 589824 + 1179648 + 75497472); // 64 MB

    k_scale_mask<<<dim3(B_ * H_), 512, 0, stream>>>(x, w_scale, b_scale, w_mask, b_mask,
                                                    scale_ws, mask_ws);
    k_pack_w<<<dim3(9, O_), 256, 0, stream>>>(weight, wbf);
    k_transpose<<<dim3(HW / 64, C_ / 64, B_), 256, 0, stream>>>(x, xT);
    k_val2<<<dim3(NPIX / 4), 256, 0, stream>>>(xT, scale_ws, mask_ws, val);
    k_gemm<<<dim3(NPIX / 128, O_ / 128), 256, 0, stream>>>(wbf, val, bias, out);
}